// Round 1
// baseline (12254.263 us; speedup 1.0000x reference)
//
#include <hip/hip_runtime.h>
#include <math.h>

#define BSZ 16
#define NH  8
#define SEQ 1024
#define DK  128
#define NT  256

__device__ __forceinline__ float block_max(float x, float* red, int tid) {
    #pragma unroll
    for (int off = 1; off < 64; off <<= 1) x = fmaxf(x, __shfl_xor(x, off, 64));
    if ((tid & 63) == 0) red[tid >> 6] = x;
    __syncthreads();
    float r = fmaxf(fmaxf(red[0], red[1]), fmaxf(red[2], red[3]));
    __syncthreads();
    return r;
}

__device__ __forceinline__ float block_sum(float x, float* red, int tid) {
    #pragma unroll
    for (int off = 1; off < 64; off <<= 1) x += __shfl_xor(x, off, 64);
    if ((tid & 63) == 0) red[tid >> 6] = x;
    __syncthreads();
    float r = (red[0] + red[1]) + (red[2] + red[3]);
    __syncthreads();
    return r;
}

__launch_bounds__(NT)
__global__ void attn_topk_kernel(const float* __restrict__ Q,
                                 const float* __restrict__ Km,
                                 const float* __restrict__ V,
                                 const int* __restrict__ kidx_ptr,
                                 float* __restrict__ out)
{
    const int qidx = blockIdx.x;     // query position 0..SEQ-1
    const int bh   = blockIdx.y;     // b*NH + h, 0..127
    const int tid  = threadIdx.x;

    float* orow = out + ((size_t)bh * SEQ + qidx) * DK;

    // Row 0 is replaced by zeros after the second softmax -> out = 0.
    if (qidx == 0) {
        for (int d = tid; d < DK; d += NT) orow[d] = 0.0f;
        return;
    }

    const int K = *kidx_ptr;         // 5
    const int nvalid = qidx + 1;     // causal: keys 0..qidx

    __shared__ float qs[DK];
    __shared__ float p[SEQ];         // scores -> exp -> normalized probs
    __shared__ float pc[SEQ];        // destructible copy for top-K
    __shared__ int   lst[SEQ];       // kept-key list (worst-case ties)
    __shared__ float wlst[SEQ];      // unnormalized softmax2 weights
    __shared__ float red[4];
    __shared__ float rv[4];
    __shared__ int   ri[4];
    __shared__ int   cnt;

    const float* qrow = Q + ((size_t)bh * SEQ + qidx) * DK;
    for (int d = tid; d < DK; d += NT) qs[d] = qrow[d];
    if (tid == 0) cnt = 0;
    __syncthreads();

    // ---- scores: s_j = (q . k_j) / sqrt(DK), j in [0, qidx] ----
    const float scale = (float)0.08838834764831845;  // 1/sqrt(128)
    const float4* k4 = (const float4*)(Km + (size_t)bh * SEQ * DK);
    for (int j = tid; j < nvalid; j += NT) {
        const float4* kr = k4 + (size_t)j * (DK / 4);
        float acc = 0.0f;
        #pragma unroll
        for (int d4 = 0; d4 < DK / 4; ++d4) {
            float4 kx = kr[d4];
            acc = fmaf(kx.x, qs[4*d4+0], acc);
            acc = fmaf(kx.y, qs[4*d4+1], acc);
            acc = fmaf(kx.z, qs[4*d4+2], acc);
            acc = fmaf(kx.w, qs[4*d4+3], acc);
        }
        p[j] = acc * scale;
    }
    __syncthreads();

    // ---- softmax 1 over valid entries (masked entries are exactly 0) ----
    float lm = -INFINITY;
    for (int j = tid; j < nvalid; j += NT) lm = fmaxf(lm, p[j]);
    const float m1 = block_max(lm, red, tid);
    float ls = 0.0f;
    for (int j = tid; j < nvalid; j += NT) { float e = expf(p[j] - m1); p[j] = e; ls += e; }
    const float Z1 = block_sum(ls, red, tid);
    const float invZ1 = 1.0f / Z1;
    for (int j = tid; j < nvalid; j += NT) p[j] *= invZ1;
    __syncthreads();
    // max of p is exp(0)*invZ1 == invZ1 (the argmax entry) — softmax2's max.
    const float m2 = invZ1;

    if (qidx >= K) {
        // ---- exact kth (5th-largest) p via K destructive block-argmax rounds ----
        for (int j = tid; j < nvalid; j += NT) pc[j] = p[j];
        __syncthreads();
        float kth = 0.0f;
        for (int r = 0; r < K; ++r) {
            float lv = -1.0f; int li = 0;
            for (int j = tid; j < nvalid; j += NT) {
                float x = pc[j];
                if (x > lv) { lv = x; li = j; }
            }
            #pragma unroll
            for (int off = 1; off < 64; off <<= 1) {
                float ov = __shfl_xor(lv, off, 64);
                int   oi = __shfl_xor(li, off, 64);
                if (ov > lv) { lv = ov; li = oi; }
            }
            if ((tid & 63) == 0) { rv[tid >> 6] = lv; ri[tid >> 6] = li; }
            __syncthreads();
            float bv = rv[0]; int bi = ri[0];
            #pragma unroll
            for (int w = 1; w < 4; ++w) if (rv[w] > bv) { bv = rv[w]; bi = ri[w]; }
            kth = bv;
            __syncthreads();
            if (tid == 0) pc[bi] = -1.0f;
            __syncthreads();
        }

        // ---- kept set: p_j >= kth; softmax2 over kept; sparse PV ----
        float lw = 0.0f;
        for (int j = tid; j < nvalid; j += NT) {
            float pj = p[j];
            if (pj >= kth) {
                float e = expf(pj - m2);
                int pos = atomicAdd(&cnt, 1);
                lst[pos]  = j;
                wlst[pos] = e;
                lw += e;
            }
        }
        const float W = block_sum(lw, red, tid);
        __syncthreads();
        const int n = cnt;
        const float invW = 1.0f / W;
        const float* vb = V + (size_t)bh * SEQ * DK;
        for (int d = tid; d < DK; d += NT) {
            float acc = 0.0f;
            for (int i = 0; i < n; ++i)
                acc = fmaf(wlst[i], vb[(size_t)lst[i] * DK + d], acc);
            orow[d] = acc * invW;
        }
    } else {
        // ---- rows 1..K-1: softmax2 over [p_0..p_q, 0, 0, ..., 0] ----
        // masked slots carry exp(0 - m2) weight -> near-uniform mix of ALL v rows
        const float em = expf(-m2);
        float zl = 0.0f;
        if (tid < nvalid) zl = expf(p[tid] - m2);
        const float Zp = block_sum(zl, red, tid);
        const float Z2 = Zp + (float)(SEQ - nvalid) * em;
        const float invZ2 = 1.0f / Z2;
        const float* vb = V + (size_t)bh * SEQ * DK;
        for (int d = tid; d < DK; d += NT) {
            float acc = 0.0f;
            for (int j = nvalid; j < SEQ; ++j) acc += vb[(size_t)j * DK + d];
            acc *= em;
            for (int j = 0; j < nvalid; ++j)
                acc = fmaf(expf(p[j] - m2), vb[(size_t)j * DK + d], acc);
            orow[d] = acc * invZ2;
        }
    }
}

extern "C" void kernel_launch(void* const* d_in, const int* in_sizes, int n_in,
                              void* d_out, int out_size, void* d_ws, size_t ws_size,
                              hipStream_t stream) {
    const float* q    = (const float*)d_in[0];
    const float* k    = (const float*)d_in[1];
    const float* v    = (const float*)d_in[2];
    // d_in[3] = mask (tril, causal) — implied by j <= qidx
    const int*   kidx = (const int*)d_in[4];
    float* out = (float*)d_out;

    dim3 grid(SEQ, BSZ * NH);
    attn_topk_kernel<<<grid, NT, 0, stream>>>(q, k, v, kidx, out);
}

// Round 2
// 1573.350 us; speedup vs baseline: 7.7886x; 7.7886x over previous
//
#include <hip/hip_runtime.h>
#include <math.h>

#define BSZ 16
#define NH  8
#define SEQ 1024
#define DK  128
#define NT  256
#define TQ  4
#define TOPK 5   // k_index is 5 in this problem's setup

// insert x into sorted-descending t[0..4], keeping top-5
__device__ __forceinline__ void ins5(float (&t)[TOPK], float x) {
    #pragma unroll
    for (int i = 0; i < TOPK; ++i) {
        float a = fmaxf(t[i], x);
        x = fminf(t[i], x);
        t[i] = a;
    }
}

__launch_bounds__(NT, 4)
__global__ void attn_topk_kernel(const float* __restrict__ Q,
                                 const float* __restrict__ Km,
                                 const float* __restrict__ V,
                                 const int* __restrict__ kidx_ptr,
                                 float* __restrict__ out)
{
    const int qbase = blockIdx.x * TQ;
    const int bh    = blockIdx.y;
    const int tid   = threadIdx.x;
    const int lane  = tid & 63;
    const int w     = tid >> 6;          // wave id 0..3 -> owns row qbase+w

    __shared__ __align__(16) float qsh[TQ][DK];
    __shared__ float s_lds[TQ][SEQ];
    __shared__ int   lst[TQ][64];
    __shared__ float wlst[TQ][64];
    __shared__ int   cnt[TQ];

    // ---- load the 4 q rows, init counters ----
    const float* qptr = Q + ((size_t)bh * SEQ + qbase) * DK;
    for (int i = tid; i < TQ * DK; i += NT) qsh[i / DK][i % DK] = qptr[i];
    if (tid < TQ) cnt[tid] = 0;
    __syncthreads();

    // ---- phase 1 (cooperative): scores for all 4 rows, j in [0, qbase+TQ) ----
    const float scale = 0.08838834764831845f;  // 1/sqrt(128)
    const float4* k4 = (const float4*)(Km + (size_t)bh * SEQ * DK);
    const float4* q4 = (const float4*)qsh;     // [TQ * 32]
    const int nvmax = qbase + TQ;
    for (int j = tid; j < nvmax; j += NT) {
        const float4* kr = k4 + (size_t)j * (DK / 4);
        float a0 = 0.f, a1 = 0.f, a2 = 0.f, a3 = 0.f;
        #pragma unroll 8
        for (int c = 0; c < DK / 4; ++c) {
            float4 kx = kr[c];
            float4 t0 = q4[0 * 32 + c];
            a0 = fmaf(kx.x, t0.x, a0); a0 = fmaf(kx.y, t0.y, a0);
            a0 = fmaf(kx.z, t0.z, a0); a0 = fmaf(kx.w, t0.w, a0);
            float4 t1 = q4[1 * 32 + c];
            a1 = fmaf(kx.x, t1.x, a1); a1 = fmaf(kx.y, t1.y, a1);
            a1 = fmaf(kx.z, t1.z, a1); a1 = fmaf(kx.w, t1.w, a1);
            float4 t2 = q4[2 * 32 + c];
            a2 = fmaf(kx.x, t2.x, a2); a2 = fmaf(kx.y, t2.y, a2);
            a2 = fmaf(kx.z, t2.z, a2); a2 = fmaf(kx.w, t2.w, a2);
            float4 t3 = q4[3 * 32 + c];
            a3 = fmaf(kx.x, t3.x, a3); a3 = fmaf(kx.y, t3.y, a3);
            a3 = fmaf(kx.z, t3.z, a3); a3 = fmaf(kx.w, t3.w, a3);
        }
        s_lds[0][j] = a0 * scale;
        s_lds[1][j] = a1 * scale;
        s_lds[2][j] = a2 * scale;
        s_lds[3][j] = a3 * scale;
    }
    __syncthreads();

    // ---- phase 2 (per-wave, no block barriers): wave w owns row q = qbase+w ----
    const int q  = qbase + w;
    const int Kv = *kidx_ptr;            // 5
    float* orow = out + ((size_t)bh * SEQ + q) * DK;

    if (q == 0) {                        // row 0 zeroed by pad_zero
        orow[lane] = 0.0f;
        orow[lane + 64] = 0.0f;
        return;
    }

    const int nv = q + 1;

    // local scan: top-5 (sorted desc) over my slice; merged t[0] is the row max
    float t[TOPK];
    #pragma unroll
    for (int i = 0; i < TOPK; ++i) t[i] = -INFINITY;
    for (int j = lane; j < nv; j += 64) ins5(t, s_lds[w][j]);
    #pragma unroll
    for (int off = 1; off < 64; off <<= 1) {
        float o[TOPK];
        #pragma unroll
        for (int i = 0; i < TOPK; ++i) o[i] = __shfl_xor(t[i], off, 64);
        #pragma unroll
        for (int i = 0; i < TOPK; ++i) ins5(t, o[i]);
    }
    const float m1 = t[0];

    // Z1 = sum exp(s - m1)
    float zl = 0.f;
    for (int j = lane; j < nv; j += 64) zl += expf(s_lds[w][j] - m1);
    #pragma unroll
    for (int off = 1; off < 64; off <<= 1) zl += __shfl_xor(zl, off, 64);
    const float Z1 = zl;
    const float invZ1 = 1.0f / Z1;
    const float m2 = invZ1;              // max prob = exp(0)*invZ1

    const float* vb = V + (size_t)bh * SEQ * DK;

    if (q >= Kv) {
        // kept set: p_j >= kth_p (ties included, matching `scores_b - kth >= 0`)
        const float kth_p = expf(t[TOPK - 1] - m1) * invZ1;
        for (int j = lane; j < nv; j += 64) {
            float pj = expf(s_lds[w][j] - m1) * invZ1;
            if (pj >= kth_p) {
                int pos = atomicAdd(&cnt[w], 1);
                if (pos < 64) {
                    lst[w][pos]  = j;
                    wlst[w][pos] = expf(pj - m2);
                }
            }
        }
        int n = cnt[w];                  // wave lockstep: all appends done
        if (n > 64) n = 64;
        float wl = (lane < n) ? wlst[w][lane] : 0.f;
        #pragma unroll
        for (int off = 1; off < 64; off <<= 1) wl += __shfl_xor(wl, off, 64);
        const float invW = 1.0f / wl;

        float a0 = 0.f, a1 = 0.f;
        for (int i = 0; i < n; ++i) {
            int jj = lst[w][i];
            float wi = wlst[w][i];
            a0 = fmaf(wi, vb[(size_t)jj * DK + lane], a0);
            a1 = fmaf(wi, vb[(size_t)jj * DK + 64 + lane], a1);
        }
        orow[lane]      = a0 * invW;
        orow[lane + 64] = a1 * invW;
    } else {
        // rows 1..Kv-1: softmax2 over [p_0..p_q, 0, 0, ...] — masked slots
        // carry weight exp(0 - m2), mixing in ALL later v rows
        const float em = expf(-m2);
        float Zp = 0.f;
        for (int j = 0; j < nv; ++j)
            Zp += expf(expf(s_lds[w][j] - m1) * invZ1 - m2);
        const float Z2 = Zp + (float)(SEQ - nv) * em;

        float a0 = 0.f, a1 = 0.f;
        #pragma unroll 4
        for (int j = nv; j < SEQ; ++j) {
            a0 += vb[(size_t)j * DK + lane];
            a1 += vb[(size_t)j * DK + 64 + lane];
        }
        a0 *= em; a1 *= em;
        for (int j = 0; j < nv; ++j) {
            float wj = expf(expf(s_lds[w][j] - m1) * invZ1 - m2);
            a0 = fmaf(wj, vb[(size_t)j * DK + lane], a0);
            a1 = fmaf(wj, vb[(size_t)j * DK + 64 + lane], a1);
        }
        const float iz = 1.0f / Z2;
        orow[lane]      = a0 * iz;
        orow[lane + 64] = a1 * iz;
    }
}

extern "C" void kernel_launch(void* const* d_in, const int* in_sizes, int n_in,
                              void* d_out, int out_size, void* d_ws, size_t ws_size,
                              hipStream_t stream) {
    const float* q    = (const float*)d_in[0];
    const float* k    = (const float*)d_in[1];
    const float* v    = (const float*)d_in[2];
    // d_in[3] = mask (tril) — implied by j <= q
    const int*   kidx = (const int*)d_in[4];
    float* out = (float*)d_out;

    dim3 grid(SEQ / TQ, BSZ * NH);
    attn_topk_kernel<<<grid, NT, 0, stream>>>(q, k, v, kidx, out);
}